// Round 11
// baseline (375.774 us; speedup 1.0000x reference)
//
#include <hip/hip_runtime.h>
#include <hip/hip_bf16.h>

typedef unsigned short ushort_t;
typedef unsigned int uint_t;
typedef unsigned char uchar_t;

typedef __attribute__((ext_vector_type(8))) short bf16x8;
typedef __attribute__((ext_vector_type(4))) float f32x4;
typedef __attribute__((ext_vector_type(2))) float f32x2;

__device__ __forceinline__ float bf2f(ushort_t u) {
    union { uint_t i; float f; } v; v.i = ((uint_t)u) << 16; return v.f;
}
__device__ __forceinline__ ushort_t f2bf(float f) {
    __hip_bfloat16 h = __float2bfloat16(f);
    ushort_t u; __builtin_memcpy(&u, &h, 2); return u;
}
__device__ __forceinline__ uchar_t f2fp8(float v) {
    int p = __builtin_amdgcn_cvt_pk_fp8_f32(v, v, 0, false);
    return (uchar_t)(p & 0xff);
}
__device__ __forceinline__ float leaky(float v) { return (v > 0.f) ? v : 0.2f * v; }

#define PO_AS1 0
#define PO_AD1 512
#define PO_B1  1024
#define PO_W2  1536
#define PO_AS2 6656
#define PO_AD2 6666
#define PO_B2  6676
#define PTOT   6686

__device__ __forceinline__ bool detect_fp32_local(const ushort_t* __restrict__ xa) {
    __shared__ int cnt;
    if (threadIdx.x == 0) cnt = 0;
    __syncthreads();
    int bad = 0;
    for (int i = threadIdx.x; i < 4096; i += 256) {
        float v = bf2f(xa[i]);
        if (!(fabsf(v) < 1e4f)) bad++;
    }
    if (bad) atomicAdd(&cnt, bad);
    __syncthreads();
    return cnt >= 16;
}

// ---- prep: W1 transpose + param normalize + deg zero + gacc/gcnt/donecnt/sync zero ----
__global__ __launch_bounds__(256) void k_prep(const void* __restrict__ x,
                                              const void* __restrict__ W1,
                                              const void* as1, const void* ad1,
                                              const void* b1, const void* W2,
                                              const void* as2, const void* ad2,
                                              const void* b2,
                                              ushort_t* __restrict__ W1t,
                                              float* __restrict__ prm,
                                              int* __restrict__ deg,
                                              float* __restrict__ gacc,
                                              int* __restrict__ flag, int N) {
    int b = blockIdx.x, t = threadIdx.x;
    if (b < 283) {
        bool isf = detect_fp32_local((const ushort_t*)x);
        if (b == 0 && t == 0) *flag = isf ? 1 : 0;
        if (b < 256) {
            int idx = b * 256 + t;
            int n = idx & 511, k = idx >> 9;
            float v = isf ? ((const float*)W1)[k * 512 + n]
                          : bf2f(((const ushort_t*)W1)[k * 512 + n]);
            W1t[n * 128 + k] = f2bf(v);
        } else {
            int i = (b - 256) * 256 + t;
            if (i < PTOT) {
                const void* src; int off;
                if (i < 512)       { src = as1; off = i; }
                else if (i < 1024) { src = ad1; off = i - 512; }
                else if (i < 1536) { src = b1;  off = i - 1024; }
                else if (i < 6656) { src = W2;  off = i - 1536; }
                else if (i < 6666) { src = as2; off = i - 6656; }
                else if (i < 6676) { src = ad2; off = i - 6666; }
                else               { src = b2;  off = i - 6676; }
                prm[i] = isf ? ((const float*)src)[off] : bf2f(((const ushort_t*)src)[off]);
            }
        }
    } else if (b < 362) {
        int i = (b - 283) * 256 + t;
        if (i < N) deg[i] = 0;
    } else {
        for (int i = t; i < 768; i += 256) gacc[i] = 0.f;   // sums+counts+donecnt+sync
    }
}

// ------ fused GEMM1 (+logits) and degree histogram; hist also records each
// edge's within-dst slot (epos) so the scatter phase needs no atomics ------
__global__ __launch_bounds__(256) void k_gemm_hist(const void* __restrict__ xraw,
                                                   const ushort_t* __restrict__ w1t,
                                                   const float* __restrict__ prm,
                                                   const int* __restrict__ ei,
                                                   const int* __restrict__ flag,
                                                   uchar_t* __restrict__ h1,
                                                   float* __restrict__ asrcf,
                                                   float* __restrict__ adstf,
                                                   int* __restrict__ deg,
                                                   int* __restrict__ epos,
                                                   int E, int Etot) {
    int b = blockIdx.x, t = threadIdx.x;
    if (b >= 1250) {
        int e = (b - 1250) * 256 + t;
        if (e < Etot) {
            int dst = (e < E) ? ei[E + e] : (e - E);
            epos[e] = atomicAdd(&deg[dst], 1);
        }
        return;
    }
    int wave = t >> 6, lane = t & 63;
    int m0 = b * 16;
    bool isf = (*flag != 0);
    __shared__ ushort_t sA[16 * 128];
    {
        ushort_t tmp[8];
        if (isf) {
            const float4* x4 = (const float4*)((const float*)xraw + (size_t)m0 * 128);
            float4 f0 = x4[2 * t], f1 = x4[2 * t + 1];
            tmp[0] = f2bf(f0.x); tmp[1] = f2bf(f0.y); tmp[2] = f2bf(f0.z); tmp[3] = f2bf(f0.w);
            tmp[4] = f2bf(f1.x); tmp[5] = f2bf(f1.y); tmp[6] = f2bf(f1.z); tmp[7] = f2bf(f1.w);
        } else {
            const uint4* x4 = (const uint4*)((const ushort_t*)xraw + (size_t)m0 * 128);
            uint4 u = x4[t];
            __builtin_memcpy(tmp, &u, 16);
        }
        *reinterpret_cast<uint4*>(&sA[t * 8]) = *reinterpret_cast<uint4*>(tmp);
    }
    __syncthreads();
    int mr = lane & 15, quad = lane >> 4;
    int n0 = wave * 128;
    f32x4 acc[8];
#pragma unroll
    for (int ct = 0; ct < 8; ++ct) acc[ct] = {0.f, 0.f, 0.f, 0.f};
#pragma unroll
    for (int kk = 0; kk < 4; ++kk) {
        bf16x8 a = *reinterpret_cast<const bf16x8*>(&sA[mr * 128 + quad * 8 + kk * 32]);
#pragma unroll
        for (int ct = 0; ct < 8; ++ct) {
            bf16x8 bb = *reinterpret_cast<const bf16x8*>(
                &w1t[(size_t)(n0 + ct * 16 + mr) * 128 + quad * 8 + kk * 32]);
            acc[ct] = __builtin_amdgcn_mfma_f32_16x16x32_bf16(a, bb, acc[ct], 0, 0, 0);
        }
    }
    int col = lane & 15;
#pragma unroll
    for (int hh = 0; hh < 2; ++hh) {
        float ps[4] = {0.f, 0.f, 0.f, 0.f}, pd[4] = {0.f, 0.f, 0.f, 0.f};
#pragma unroll
        for (int c4 = 0; c4 < 4; ++c4) {
            int ct = hh * 4 + c4;
            int abscol = n0 + ct * 16 + col;
            float asv = prm[PO_AS1 + abscol];
            float adv = prm[PO_AD1 + abscol];
#pragma unroll
            for (int r = 0; r < 4; ++r) {
                h1[(size_t)(m0 + quad * 4 + r) * 512 + abscol] = f2fp8(acc[ct][r]);
                ps[r] += acc[ct][r] * asv;
                pd[r] += acc[ct][r] * adv;
            }
        }
#pragma unroll
        for (int off = 1; off <= 8; off <<= 1) {
#pragma unroll
            for (int r = 0; r < 4; ++r) {
                ps[r] += __shfl_xor(ps[r], off, 64);
                pd[r] += __shfl_xor(pd[r], off, 64);
            }
        }
        if (col == 0) {
            int head = 2 * wave + hh;
#pragma unroll
            for (int r = 0; r < 4; ++r) {
                asrcf[(m0 + quad * 4 + r) * 8 + head] = ps[r];
                adstf[(m0 + quad * 4 + r) * 8 + head] = pd[r];
            }
        }
    }
}

// ---- merged scan + scatter (one dispatch). 79 scan blocks + 1329 scatter
// blocks = 1408, ALL co-resident (<=2048 at 4 waves/block) -> the scatter
// blocks' spin on the device-scope flag cannot deadlock regardless of
// dispatch order. rowptr visibility: per-thread threadfence + release-add;
// readers use agent-scope atomic loads (coherent point, no stale-L2). ----
__global__ __launch_bounds__(256) void k_scansc(const int* __restrict__ deg,
                                                int* __restrict__ rowptr,
                                                const int* __restrict__ ei,
                                                const int* __restrict__ epos,
                                                int* __restrict__ csr_src,
                                                int* __restrict__ syncf,
                                                int E, int Etot, int N, int nscan) {
    int b = blockIdx.x, t = threadIdx.x;
    if (b < nscan) {
        int lane = t & 63, wv = t >> 6;
        __shared__ int ws[4], wt[4];
        __shared__ int sbase;
        int limit = b * 256;
        int p0 = 0, p1 = 0, p2 = 0, p3 = 0;
        int i = t;
        for (; i + 768 < limit; i += 1024) {
            p0 += deg[i]; p1 += deg[i + 256]; p2 += deg[i + 512]; p3 += deg[i + 768];
        }
        for (; i < limit; i += 256) p0 += deg[i];
        int partial = (p0 + p1) + (p2 + p3);
#pragma unroll
        for (int off = 32; off; off >>= 1) partial += __shfl_xor(partial, off, 64);
        if (lane == 0) ws[wv] = partial;
        __syncthreads();
        if (t == 0) sbase = ws[0] + ws[1] + ws[2] + ws[3];
        __syncthreads();
        int base = sbase;
        i = limit + t;
        int v = (i < N) ? deg[i] : 0;
        int inc = v;
#pragma unroll
        for (int off = 1; off < 64; off <<= 1) {
            int u = __shfl_up(inc, off, 64);
            if (lane >= off) inc += u;
        }
        if (lane == 63) wt[wv] = inc;
        __syncthreads();
        int woff = 0;
        for (int w = 0; w < 4; ++w) if (w < wv) woff += wt[w];
        int excl = base + woff + inc - v;
        if (i < N) rowptr[i + 1] = excl + v;
        if (i == 0) rowptr[0] = 0;
        __threadfence();
        __syncthreads();
        if (t == 0)
            __hip_atomic_fetch_add(syncf, 1, __ATOMIC_RELEASE, __HIP_MEMORY_SCOPE_AGENT);
    } else {
        if (t == 0) {
            while (__hip_atomic_load(syncf, __ATOMIC_ACQUIRE, __HIP_MEMORY_SCOPE_AGENT) < nscan)
                __builtin_amdgcn_s_sleep(2);
        }
        __syncthreads();
        int e = (b - nscan) * 256 + t;
        if (e >= Etot) return;
        int src, dst;
        if (e < E) { src = ei[e]; dst = ei[E + e]; } else { src = dst = e - E; }
        int rp = __hip_atomic_load(&rowptr[dst], __ATOMIC_RELAXED, __HIP_MEMORY_SCOPE_AGENT);
        csr_src[rp + epos[e]] = src;
    }
}

// --- layer-1 agg + ELU + layer-2 linear&logits. R0/R9-verified structure:
// ONE wave per node (4/block), 8-edge batches, in-loop asrcf gather +
// leaky + exp. h2 bf16 32B rows + as2/ad2 epilogue. Single dispatch. ---
__global__ __launch_bounds__(256) void k_agg1(const uchar_t* __restrict__ h1,
                                              const float* __restrict__ asrcf,
                                              const float* __restrict__ adstf,
                                              const int* __restrict__ rowptr,
                                              const int* __restrict__ csr_src,
                                              const float* __restrict__ prm,
                                              ushort_t* __restrict__ h2,
                                              float* __restrict__ asrc2f,
                                              float* __restrict__ adst2f) {
    int n = blockIdx.x * 4 + (threadIdx.x >> 6);
    int lane = threadIdx.x & 63;
    int hh = lane >> 3;
    int cb = lane * 8;
    int start = rowptr[n], end = rowptr[n + 1];
    int deg = end - start;
    float adh = adstf[n * 8 + hh];
    float a0 = 0.f, a1 = 0.f, a2 = 0.f, a3 = 0.f, a4 = 0.f, a5 = 0.f, a6 = 0.f, a7 = 0.f;
    float den = 0.f;
    for (int base = 0; base < deg; base += 64) {
        int m = min(64, deg - base);
        int sIdx = csr_src[start + base + min(lane, m - 1)];
        for (int g = 0; g < m; g += 8) {
            int s[8]; float lo[8]; uint2 p[8];
#pragma unroll
            for (int j = 0; j < 8; ++j)
                s[j] = __shfl(sIdx, min(g + j, m - 1), 64);
#pragma unroll
            for (int j = 0; j < 8; ++j)
                lo[j] = asrcf[s[j] * 8 + hh];
#pragma unroll
            for (int j = 0; j < 8; ++j)
                p[j] = *reinterpret_cast<const uint2*>(&h1[(size_t)s[j] * 512 + cb]);
#pragma unroll
            for (int j = 0; j < 8; ++j) {
                float we = (g + j < m) ? __expf(leaky(lo[j] + adh)) : 0.f;
                den += we;
                f32x2 q0 = __builtin_amdgcn_cvt_pk_f32_fp8((int)p[j].x, false);
                f32x2 q1 = __builtin_amdgcn_cvt_pk_f32_fp8((int)p[j].x, true);
                f32x2 q2 = __builtin_amdgcn_cvt_pk_f32_fp8((int)p[j].y, false);
                f32x2 q3 = __builtin_amdgcn_cvt_pk_f32_fp8((int)p[j].y, true);
                a0 += we * q0.x; a1 += we * q0.y;
                a2 += we * q1.x; a3 += we * q1.y;
                a4 += we * q2.x; a5 += we * q2.y;
                a6 += we * q3.x; a7 += we * q3.y;
            }
        }
    }
    float inv = 1.f / (den + 1e-16f);
    float r[8] = {a0, a1, a2, a3, a4, a5, a6, a7};
    float p2[10];
#pragma unroll
    for (int c = 0; c < 10; ++c) p2[c] = 0.f;
#pragma unroll
    for (int j = 0; j < 8; ++j) {
        float rv = r[j] * inv + prm[PO_B1 + cb + j];
        rv = (rv > 0.f) ? rv : expm1f(rv);    // ELU
        const float2* wrow = reinterpret_cast<const float2*>(&prm[PO_W2 + (cb + j) * 10]);
        float2 w01 = wrow[0], w23 = wrow[1], w45 = wrow[2], w67 = wrow[3], w89 = wrow[4];
        p2[0] += rv * w01.x; p2[1] += rv * w01.y;
        p2[2] += rv * w23.x; p2[3] += rv * w23.y;
        p2[4] += rv * w45.x; p2[5] += rv * w45.y;
        p2[6] += rv * w67.x; p2[7] += rv * w67.y;
        p2[8] += rv * w89.x; p2[9] += rv * w89.y;
    }
#pragma unroll
    for (int c = 0; c < 10; ++c)
#pragma unroll
        for (int off = 32; off; off >>= 1)
            p2[c] += __shfl_xor(p2[c], off, 64);
    if (lane == 0) {
        float as = 0.f, ad = 0.f;
#pragma unroll
        for (int c = 0; c < 10; ++c) {
            h2[(size_t)n * 16 + c] = f2bf(p2[c]);   // bf16 32B rows
            as += p2[c] * prm[PO_AS2 + c];
            ad += p2[c] * prm[PO_AD2 + c];
        }
        asrc2f[n] = as; adst2f[n] = ad;
    }
}

// ------- layer-2 softmax+agg, 16 lanes/node, fused mean-pool + counts + final -------
__global__ __launch_bounds__(256) void k_agg2f(const ushort_t* __restrict__ h2,
                                               const float* __restrict__ asrc2f,
                                               const float* __restrict__ adst2f,
                                               const int* __restrict__ rowptr,
                                               const int* __restrict__ csr_src,
                                               const float* __restrict__ prm,
                                               const int* __restrict__ batch,
                                               float* __restrict__ gacc,
                                               float* __restrict__ gcnt,
                                               int* __restrict__ donecnt,
                                               const int* __restrict__ flag,
                                               void* __restrict__ dout) {
    int t = threadIdx.x;
    int grp = t >> 4, l = t & 15;
    int n = blockIdx.x * 16 + grp;
    int start = rowptr[n], end = rowptr[n + 1];
    float adn = adst2f[n];
    float den = 0.f;
    float oc[10];
#pragma unroll
    for (int c = 0; c < 10; ++c) oc[c] = 0.f;
    for (int e = start + l; e < end; e += 16) {
        int s = csr_src[e];
        float lo = asrc2f[s];
        const uint_t* hp = (const uint_t*)(h2 + (size_t)s * 16);
        uint4 ha = *(const uint4*)hp;
        uint_t hb = hp[4];
        float ee = __expf(leaky(lo + adn));
        den += ee;
        oc[0] += ee * bf2f(ha.x & 0xffff); oc[1] += ee * bf2f(ha.x >> 16);
        oc[2] += ee * bf2f(ha.y & 0xffff); oc[3] += ee * bf2f(ha.y >> 16);
        oc[4] += ee * bf2f(ha.z & 0xffff); oc[5] += ee * bf2f(ha.z >> 16);
        oc[6] += ee * bf2f(ha.w & 0xffff); oc[7] += ee * bf2f(ha.w >> 16);
        oc[8] += ee * bf2f(hb & 0xffff);   oc[9] += ee * bf2f(hb >> 16);
    }
#pragma unroll
    for (int off = 8; off; off >>= 1) {
        den += __shfl_xor(den, off, 64);
#pragma unroll
        for (int c = 0; c < 10; ++c) oc[c] += __shfl_xor(oc[c], off, 64);
    }
    __shared__ float sres[16][12];
    __shared__ int sg[16];
    if (l == 0) {
        float invd = 1.f / (den + 1e-16f);
#pragma unroll
        for (int c = 0; c < 10; ++c) sres[grp][c] = oc[c] * invd + prm[PO_B2 + c];
        sres[grp][10] = 1.f;
        sg[grp] = batch[n];
    }
    __syncthreads();
    if (t < 11) {
        int c = t;
        float run = sres[0][c]; int g = sg[0];
        for (int k = 1; k < 16; ++k) {
            if (sg[k] != g) {
                atomicAdd(c < 10 ? &gacc[g * 10 + c] : &gcnt[g], run);
                g = sg[k]; run = 0.f;
            }
            run += sres[k][c];
        }
        atomicAdd(c < 10 ? &gacc[g * 10 + c] : &gcnt[g], run);
    }
    // ---- last block performs the final divide + store ----
    __syncthreads();
    __shared__ int slast;
    if (t == 0) {
        __threadfence();
        int d = atomicAdd(donecnt, 1);
        slast = (d == (int)gridDim.x - 1) ? 1 : 0;
    }
    __syncthreads();
    if (slast && t < 64) {
        __threadfence();
        bool isf = (*flag != 0);
        const volatile float* ga = (const volatile float*)gacc;
        const volatile float* gc = (const volatile float*)gcnt;
        float cnt = fmaxf(gc[t], 1.f);
        for (int c = 0; c < 10; ++c) {
            float r = ga[t * 10 + c] / cnt;
            if (isf) ((float*)dout)[t * 10 + c] = r;
            else     ((ushort_t*)dout)[t * 10 + c] = f2bf(r);
        }
    }
}

extern "C" void kernel_launch(void* const* d_in, const int* in_sizes, int n_in,
                              void* d_out, int out_size, void* d_ws, size_t ws_size,
                              hipStream_t stream) {
    const void* x   = d_in[0];
    const int* ei   = (const int*)d_in[1];
    const int* batch= (const int*)d_in[2];
    const void* W1  = d_in[3];
    const void* as1 = d_in[4];
    const void* ad1 = d_in[5];
    const void* b1  = d_in[6];
    const void* W2  = d_in[7];
    const void* as2 = d_in[8];
    const void* ad2 = d_in[9];
    const void* b2  = d_in[10];

    constexpr int N = 20000, E = 320000, Etot = E + N;
    constexpr int histBlocks = (Etot + 255) / 256;   // 1329
    constexpr int scanBlocks = (N + 255) / 256;      // 79

    char* p = (char*)d_ws;
    auto alloc = [&](size_t bytes) {
        char* r = p; p += (bytes + 255) & ~(size_t)255; return r;
    };
    int* flag       = (int*)alloc(256);
    float* prm      = (float*)alloc((size_t)PTOT * 4);
    ushort_t* w1t   = (ushort_t*)alloc(512 * 128 * 2);
    uchar_t* h1     = (uchar_t*)alloc((size_t)N * 512);           // 10.24 MB fp8
    float* asrc1f   = (float*)alloc((size_t)N * 8 * 4);
    float* adst1f   = (float*)alloc((size_t)N * 8 * 4);
    float* asrc2f   = (float*)alloc((size_t)N * 4);
    float* adst2f   = (float*)alloc((size_t)N * 4);
    ushort_t* h2    = (ushort_t*)alloc((size_t)N * 16 * 2);       // bf16 32B rows
    float* gacc     = (float*)alloc((size_t)768 * 4);             // sums+counts+donecnt+sync
    int* deg        = (int*)alloc((size_t)N * 4);
    int* rowptr     = (int*)alloc((size_t)(N + 1) * 4);
    int* epos       = (int*)alloc((size_t)Etot * 4);
    int* csr_src    = (int*)alloc((size_t)(Etot + 64) * 4);
    float* gcnt     = gacc + 640;
    int* donecnt    = (int*)(gacc + 704);
    int* syncf      = (int*)(gacc + 705);

    k_prep<<<363, 256, 0, stream>>>(x, W1, as1, ad1, b1, W2, as2, ad2, b2,
                                    w1t, prm, deg, gacc, flag, N);
    k_gemm_hist<<<1250 + histBlocks, 256, 0, stream>>>(x, w1t, prm, ei, flag, h1,
                                                       asrc1f, adst1f, deg, epos, E, Etot);
    k_scansc<<<scanBlocks + histBlocks, 256, 0, stream>>>(deg, rowptr, ei, epos,
                                                          csr_src, syncf, E, Etot, N,
                                                          scanBlocks);
    k_agg1<<<N / 4, 256, 0, stream>>>(h1, asrc1f, adst1f, rowptr, csr_src, prm,
                                      h2, asrc2f, adst2f);
    k_agg2f<<<N / 16, 256, 0, stream>>>(h2, asrc2f, adst2f, rowptr, csr_src, prm,
                                        batch, gacc, gcnt, donecnt, flag, d_out);
}

// Round 12
// 227.399 us; speedup vs baseline: 1.6525x; 1.6525x over previous
//
#include <hip/hip_runtime.h>
#include <hip/hip_bf16.h>

typedef unsigned short ushort_t;
typedef unsigned int uint_t;
typedef unsigned char uchar_t;

typedef __attribute__((ext_vector_type(8))) short bf16x8;
typedef __attribute__((ext_vector_type(4))) float f32x4;
typedef __attribute__((ext_vector_type(2))) float f32x2;

__device__ __forceinline__ float bf2f(ushort_t u) {
    union { uint_t i; float f; } v; v.i = ((uint_t)u) << 16; return v.f;
}
__device__ __forceinline__ ushort_t f2bf(float f) {
    __hip_bfloat16 h = __float2bfloat16(f);
    ushort_t u; __builtin_memcpy(&u, &h, 2); return u;
}
__device__ __forceinline__ uchar_t f2fp8(float v) {
    int p = __builtin_amdgcn_cvt_pk_fp8_f32(v, v, 0, false);
    return (uchar_t)(p & 0xff);
}
__device__ __forceinline__ float leaky(float v) { return (v > 0.f) ? v : 0.2f * v; }

#define PO_AS1 0
#define PO_AD1 512
#define PO_B1  1024
#define PO_W2  1536
#define PO_AS2 6656
#define PO_AD2 6666
#define PO_B2  6676
#define PTOT   6686

__device__ __forceinline__ bool detect_fp32_local(const ushort_t* __restrict__ xa) {
    __shared__ int cnt;
    if (threadIdx.x == 0) cnt = 0;
    __syncthreads();
    int bad = 0;
    for (int i = threadIdx.x; i < 4096; i += 256) {
        float v = bf2f(xa[i]);
        if (!(fabsf(v) < 1e4f)) bad++;
    }
    if (bad) atomicAdd(&cnt, bad);
    __syncthreads();
    return cnt >= 16;
}

// ---- prep: W1 transpose + param normalize + deg zero + gacc/gcnt/donecnt zero ----
__global__ __launch_bounds__(256) void k_prep(const void* __restrict__ x,
                                              const void* __restrict__ W1,
                                              const void* as1, const void* ad1,
                                              const void* b1, const void* W2,
                                              const void* as2, const void* ad2,
                                              const void* b2,
                                              ushort_t* __restrict__ W1t,
                                              float* __restrict__ prm,
                                              int* __restrict__ deg,
                                              float* __restrict__ gacc,
                                              int* __restrict__ flag, int N) {
    int b = blockIdx.x, t = threadIdx.x;
    if (b < 283) {
        bool isf = detect_fp32_local((const ushort_t*)x);
        if (b == 0 && t == 0) *flag = isf ? 1 : 0;
        if (b < 256) {
            int idx = b * 256 + t;
            int n = idx & 511, k = idx >> 9;
            float v = isf ? ((const float*)W1)[k * 512 + n]
                          : bf2f(((const ushort_t*)W1)[k * 512 + n]);
            W1t[n * 128 + k] = f2bf(v);
        } else {
            int i = (b - 256) * 256 + t;
            if (i < PTOT) {
                const void* src; int off;
                if (i < 512)       { src = as1; off = i; }
                else if (i < 1024) { src = ad1; off = i - 512; }
                else if (i < 1536) { src = b1;  off = i - 1024; }
                else if (i < 6656) { src = W2;  off = i - 1536; }
                else if (i < 6666) { src = as2; off = i - 6656; }
                else if (i < 6676) { src = ad2; off = i - 6666; }
                else               { src = b2;  off = i - 6676; }
                prm[i] = isf ? ((const float*)src)[off] : bf2f(((const ushort_t*)src)[off]);
            }
        }
    } else if (b < 362) {
        int i = (b - 283) * 256 + t;
        if (i < N) deg[i] = 0;
    } else {
        for (int i = t; i < 768; i += 256) gacc[i] = 0.f;   // sums+counts+donecnt
    }
}

// ------ fused GEMM1 (+logits) and degree histogram; hist also records each
// edge's within-dst slot (epos) so k_scatter needs no atomics ------
__global__ __launch_bounds__(256) void k_gemm_hist(const void* __restrict__ xraw,
                                                   const ushort_t* __restrict__ w1t,
                                                   const float* __restrict__ prm,
                                                   const int* __restrict__ ei,
                                                   const int* __restrict__ flag,
                                                   uchar_t* __restrict__ h1,
                                                   float* __restrict__ asrcf,
                                                   float* __restrict__ adstf,
                                                   int* __restrict__ deg,
                                                   int* __restrict__ epos,
                                                   int E, int Etot) {
    int b = blockIdx.x, t = threadIdx.x;
    if (b >= 1250) {
        int e = (b - 1250) * 256 + t;
        if (e < Etot) {
            int dst = (e < E) ? ei[E + e] : (e - E);
            epos[e] = atomicAdd(&deg[dst], 1);
        }
        return;
    }
    int wave = t >> 6, lane = t & 63;
    int m0 = b * 16;
    bool isf = (*flag != 0);
    __shared__ ushort_t sA[16 * 128];
    {
        ushort_t tmp[8];
        if (isf) {
            const float4* x4 = (const float4*)((const float*)xraw + (size_t)m0 * 128);
            float4 f0 = x4[2 * t], f1 = x4[2 * t + 1];
            tmp[0] = f2bf(f0.x); tmp[1] = f2bf(f0.y); tmp[2] = f2bf(f0.z); tmp[3] = f2bf(f0.w);
            tmp[4] = f2bf(f1.x); tmp[5] = f2bf(f1.y); tmp[6] = f2bf(f1.z); tmp[7] = f2bf(f1.w);
        } else {
            const uint4* x4 = (const uint4*)((const ushort_t*)xraw + (size_t)m0 * 128);
            uint4 u = x4[t];
            __builtin_memcpy(tmp, &u, 16);
        }
        *reinterpret_cast<uint4*>(&sA[t * 8]) = *reinterpret_cast<uint4*>(tmp);
    }
    __syncthreads();
    int mr = lane & 15, quad = lane >> 4;
    int n0 = wave * 128;
    f32x4 acc[8];
#pragma unroll
    for (int ct = 0; ct < 8; ++ct) acc[ct] = {0.f, 0.f, 0.f, 0.f};
#pragma unroll
    for (int kk = 0; kk < 4; ++kk) {
        bf16x8 a = *reinterpret_cast<const bf16x8*>(&sA[mr * 128 + quad * 8 + kk * 32]);
#pragma unroll
        for (int ct = 0; ct < 8; ++ct) {
            bf16x8 bb = *reinterpret_cast<const bf16x8*>(
                &w1t[(size_t)(n0 + ct * 16 + mr) * 128 + quad * 8 + kk * 32]);
            acc[ct] = __builtin_amdgcn_mfma_f32_16x16x32_bf16(a, bb, acc[ct], 0, 0, 0);
        }
    }
    int col = lane & 15;
#pragma unroll
    for (int hh = 0; hh < 2; ++hh) {
        float ps[4] = {0.f, 0.f, 0.f, 0.f}, pd[4] = {0.f, 0.f, 0.f, 0.f};
#pragma unroll
        for (int c4 = 0; c4 < 4; ++c4) {
            int ct = hh * 4 + c4;
            int abscol = n0 + ct * 16 + col;
            float asv = prm[PO_AS1 + abscol];
            float adv = prm[PO_AD1 + abscol];
#pragma unroll
            for (int r = 0; r < 4; ++r) {
                h1[(size_t)(m0 + quad * 4 + r) * 512 + abscol] = f2fp8(acc[ct][r]);
                ps[r] += acc[ct][r] * asv;
                pd[r] += acc[ct][r] * adv;
            }
        }
#pragma unroll
        for (int off = 1; off <= 8; off <<= 1) {
#pragma unroll
            for (int r = 0; r < 4; ++r) {
                ps[r] += __shfl_xor(ps[r], off, 64);
                pd[r] += __shfl_xor(pd[r], off, 64);
            }
        }
        if (col == 0) {
            int head = 2 * wave + hh;
#pragma unroll
            for (int r = 0; r < 4; ++r) {
                asrcf[(m0 + quad * 4 + r) * 8 + head] = ps[r];
                adstf[(m0 + quad * 4 + r) * 8 + head] = pd[r];
            }
        }
    }
}

// ---- exclusive scan (rowptr only) ----
__global__ __launch_bounds__(256) void k_scan(const int* __restrict__ deg,
                                              int* __restrict__ rowptr, int N) {
    int b = blockIdx.x, t = threadIdx.x;
    int lane = t & 63, wv = t >> 6;
    __shared__ int ws[4], wt[4];
    __shared__ int sbase;
    int limit = b * 256;
    int p0 = 0, p1 = 0, p2 = 0, p3 = 0;
    int i = t;
    for (; i + 768 < limit; i += 1024) {
        p0 += deg[i]; p1 += deg[i + 256]; p2 += deg[i + 512]; p3 += deg[i + 768];
    }
    for (; i < limit; i += 256) p0 += deg[i];
    int partial = (p0 + p1) + (p2 + p3);
#pragma unroll
    for (int off = 32; off; off >>= 1) partial += __shfl_xor(partial, off, 64);
    if (lane == 0) ws[wv] = partial;
    __syncthreads();
    if (t == 0) sbase = ws[0] + ws[1] + ws[2] + ws[3];
    __syncthreads();
    int base = sbase;
    i = limit + t;
    int v = (i < N) ? deg[i] : 0;
    int inc = v;
#pragma unroll
    for (int off = 1; off < 64; off <<= 1) {
        int u = __shfl_up(inc, off, 64);
        if (lane >= off) inc += u;
    }
    if (lane == 63) wt[wv] = inc;
    __syncthreads();
    int woff = 0;
    for (int w = 0; w < 4; ++w) if (w < wv) woff += wt[w];
    int excl = base + woff + inc - v;
    if (i < N) rowptr[i + 1] = excl + v;
    if (i == 0) rowptr[0] = 0;
}

// ---- atomic-free scatter: slot precomputed in hist (epos) ----
__global__ __launch_bounds__(256) void k_scatter(const int* __restrict__ ei,
                                                 const int* __restrict__ rowptr,
                                                 const int* __restrict__ epos,
                                                 int* __restrict__ csr_src,
                                                 int E, int Etot) {
    int e = blockIdx.x * 256 + threadIdx.x;
    if (e >= Etot) return;
    int src, dst;
    if (e < E) { src = ei[e]; dst = ei[E + e]; } else { src = dst = e - E; }
    csr_src[rowptr[dst] + epos[e]] = src;
}

// --- layer-1 agg + ELU + layer-2 linear&logits. R0/R9-verified structure:
// ONE wave per node (4/block), 8-edge batches, in-loop asrcf gather +
// leaky + exp. h2 bf16 32B rows + as2/ad2 epilogue. Single dispatch. ---
__global__ __launch_bounds__(256) void k_agg1(const uchar_t* __restrict__ h1,
                                              const float* __restrict__ asrcf,
                                              const float* __restrict__ adstf,
                                              const int* __restrict__ rowptr,
                                              const int* __restrict__ csr_src,
                                              const float* __restrict__ prm,
                                              ushort_t* __restrict__ h2,
                                              float* __restrict__ asrc2f,
                                              float* __restrict__ adst2f) {
    int n = blockIdx.x * 4 + (threadIdx.x >> 6);
    int lane = threadIdx.x & 63;
    int hh = lane >> 3;
    int cb = lane * 8;
    int start = rowptr[n], end = rowptr[n + 1];
    int deg = end - start;
    float adh = adstf[n * 8 + hh];
    float a0 = 0.f, a1 = 0.f, a2 = 0.f, a3 = 0.f, a4 = 0.f, a5 = 0.f, a6 = 0.f, a7 = 0.f;
    float den = 0.f;
    for (int base = 0; base < deg; base += 64) {
        int m = min(64, deg - base);
        int sIdx = csr_src[start + base + min(lane, m - 1)];
        for (int g = 0; g < m; g += 8) {
            int s[8]; float lo[8]; uint2 p[8];
#pragma unroll
            for (int j = 0; j < 8; ++j)
                s[j] = __shfl(sIdx, min(g + j, m - 1), 64);
#pragma unroll
            for (int j = 0; j < 8; ++j)
                lo[j] = asrcf[s[j] * 8 + hh];
#pragma unroll
            for (int j = 0; j < 8; ++j)
                p[j] = *reinterpret_cast<const uint2*>(&h1[(size_t)s[j] * 512 + cb]);
#pragma unroll
            for (int j = 0; j < 8; ++j) {
                float we = (g + j < m) ? __expf(leaky(lo[j] + adh)) : 0.f;
                den += we;
                f32x2 q0 = __builtin_amdgcn_cvt_pk_f32_fp8((int)p[j].x, false);
                f32x2 q1 = __builtin_amdgcn_cvt_pk_f32_fp8((int)p[j].x, true);
                f32x2 q2 = __builtin_amdgcn_cvt_pk_f32_fp8((int)p[j].y, false);
                f32x2 q3 = __builtin_amdgcn_cvt_pk_f32_fp8((int)p[j].y, true);
                a0 += we * q0.x; a1 += we * q0.y;
                a2 += we * q1.x; a3 += we * q1.y;
                a4 += we * q2.x; a5 += we * q2.y;
                a6 += we * q3.x; a7 += we * q3.y;
            }
        }
    }
    float inv = 1.f / (den + 1e-16f);
    float r[8] = {a0, a1, a2, a3, a4, a5, a6, a7};
    float p2[10];
#pragma unroll
    for (int c = 0; c < 10; ++c) p2[c] = 0.f;
#pragma unroll
    for (int j = 0; j < 8; ++j) {
        float rv = r[j] * inv + prm[PO_B1 + cb + j];
        rv = (rv > 0.f) ? rv : expm1f(rv);    // ELU
        const float2* wrow = reinterpret_cast<const float2*>(&prm[PO_W2 + (cb + j) * 10]);
        float2 w01 = wrow[0], w23 = wrow[1], w45 = wrow[2], w67 = wrow[3], w89 = wrow[4];
        p2[0] += rv * w01.x; p2[1] += rv * w01.y;
        p2[2] += rv * w23.x; p2[3] += rv * w23.y;
        p2[4] += rv * w45.x; p2[5] += rv * w45.y;
        p2[6] += rv * w67.x; p2[7] += rv * w67.y;
        p2[8] += rv * w89.x; p2[9] += rv * w89.y;
    }
#pragma unroll
    for (int c = 0; c < 10; ++c)
#pragma unroll
        for (int off = 32; off; off >>= 1)
            p2[c] += __shfl_xor(p2[c], off, 64);
    if (lane == 0) {
        float as = 0.f, ad = 0.f;
#pragma unroll
        for (int c = 0; c < 10; ++c) {
            h2[(size_t)n * 16 + c] = f2bf(p2[c]);   // bf16 32B rows
            as += p2[c] * prm[PO_AS2 + c];
            ad += p2[c] * prm[PO_AD2 + c];
        }
        asrc2f[n] = as; adst2f[n] = ad;
    }
}

// ------- layer-2 softmax+agg, 16 lanes/node, fused mean-pool + counts + final -------
__global__ __launch_bounds__(256) void k_agg2f(const ushort_t* __restrict__ h2,
                                               const float* __restrict__ asrc2f,
                                               const float* __restrict__ adst2f,
                                               const int* __restrict__ rowptr,
                                               const int* __restrict__ csr_src,
                                               const float* __restrict__ prm,
                                               const int* __restrict__ batch,
                                               float* __restrict__ gacc,
                                               float* __restrict__ gcnt,
                                               int* __restrict__ donecnt,
                                               const int* __restrict__ flag,
                                               void* __restrict__ dout) {
    int t = threadIdx.x;
    int grp = t >> 4, l = t & 15;
    int n = blockIdx.x * 16 + grp;
    int start = rowptr[n], end = rowptr[n + 1];
    float adn = adst2f[n];
    float den = 0.f;
    float oc[10];
#pragma unroll
    for (int c = 0; c < 10; ++c) oc[c] = 0.f;
    for (int e = start + l; e < end; e += 16) {
        int s = csr_src[e];
        float lo = asrc2f[s];
        const uint_t* hp = (const uint_t*)(h2 + (size_t)s * 16);
        uint4 ha = *(const uint4*)hp;
        uint_t hb = hp[4];
        float ee = __expf(leaky(lo + adn));
        den += ee;
        oc[0] += ee * bf2f(ha.x & 0xffff); oc[1] += ee * bf2f(ha.x >> 16);
        oc[2] += ee * bf2f(ha.y & 0xffff); oc[3] += ee * bf2f(ha.y >> 16);
        oc[4] += ee * bf2f(ha.z & 0xffff); oc[5] += ee * bf2f(ha.z >> 16);
        oc[6] += ee * bf2f(ha.w & 0xffff); oc[7] += ee * bf2f(ha.w >> 16);
        oc[8] += ee * bf2f(hb & 0xffff);   oc[9] += ee * bf2f(hb >> 16);
    }
#pragma unroll
    for (int off = 8; off; off >>= 1) {
        den += __shfl_xor(den, off, 64);
#pragma unroll
        for (int c = 0; c < 10; ++c) oc[c] += __shfl_xor(oc[c], off, 64);
    }
    __shared__ float sres[16][12];
    __shared__ int sg[16];
    if (l == 0) {
        float invd = 1.f / (den + 1e-16f);
#pragma unroll
        for (int c = 0; c < 10; ++c) sres[grp][c] = oc[c] * invd + prm[PO_B2 + c];
        sres[grp][10] = 1.f;
        sg[grp] = batch[n];
    }
    __syncthreads();
    if (t < 11) {
        int c = t;
        float run = sres[0][c]; int g = sg[0];
        for (int k = 1; k < 16; ++k) {
            if (sg[k] != g) {
                atomicAdd(c < 10 ? &gacc[g * 10 + c] : &gcnt[g], run);
                g = sg[k]; run = 0.f;
            }
            run += sres[k][c];
        }
        atomicAdd(c < 10 ? &gacc[g * 10 + c] : &gcnt[g], run);
    }
    // ---- last block performs the final divide + store ----
    __syncthreads();
    __shared__ int slast;
    if (t == 0) {
        __threadfence();
        int d = atomicAdd(donecnt, 1);
        slast = (d == (int)gridDim.x - 1) ? 1 : 0;
    }
    __syncthreads();
    if (slast && t < 64) {
        __threadfence();
        bool isf = (*flag != 0);
        const volatile float* ga = (const volatile float*)gacc;
        const volatile float* gc = (const volatile float*)gcnt;
        float cnt = fmaxf(gc[t], 1.f);
        for (int c = 0; c < 10; ++c) {
            float r = ga[t * 10 + c] / cnt;
            if (isf) ((float*)dout)[t * 10 + c] = r;
            else     ((ushort_t*)dout)[t * 10 + c] = f2bf(r);
        }
    }
}

extern "C" void kernel_launch(void* const* d_in, const int* in_sizes, int n_in,
                              void* d_out, int out_size, void* d_ws, size_t ws_size,
                              hipStream_t stream) {
    const void* x   = d_in[0];
    const int* ei   = (const int*)d_in[1];
    const int* batch= (const int*)d_in[2];
    const void* W1  = d_in[3];
    const void* as1 = d_in[4];
    const void* ad1 = d_in[5];
    const void* b1  = d_in[6];
    const void* W2  = d_in[7];
    const void* as2 = d_in[8];
    const void* ad2 = d_in[9];
    const void* b2  = d_in[10];

    constexpr int N = 20000, E = 320000, Etot = E + N;
    constexpr int histBlocks = (Etot + 255) / 256;

    char* p = (char*)d_ws;
    auto alloc = [&](size_t bytes) {
        char* r = p; p += (bytes + 255) & ~(size_t)255; return r;
    };
    int* flag       = (int*)alloc(256);
    float* prm      = (float*)alloc((size_t)PTOT * 4);
    ushort_t* w1t   = (ushort_t*)alloc(512 * 128 * 2);
    uchar_t* h1     = (uchar_t*)alloc((size_t)N * 512);           // 10.24 MB fp8
    float* asrc1f   = (float*)alloc((size_t)N * 8 * 4);
    float* adst1f   = (float*)alloc((size_t)N * 8 * 4);
    float* asrc2f   = (float*)alloc((size_t)N * 4);
    float* adst2f   = (float*)alloc((size_t)N * 4);
    ushort_t* h2    = (ushort_t*)alloc((size_t)N * 16 * 2);       // bf16 32B rows
    float* gacc     = (float*)alloc((size_t)768 * 4);             // sums+counts+donecnt
    int* deg        = (int*)alloc((size_t)N * 4);
    int* rowptr     = (int*)alloc((size_t)(N + 1) * 4);
    int* epos       = (int*)alloc((size_t)Etot * 4);
    int* csr_src    = (int*)alloc((size_t)(Etot + 64) * 4);
    float* gcnt     = gacc + 640;
    int* donecnt    = (int*)(gacc + 704);

    k_prep<<<363, 256, 0, stream>>>(x, W1, as1, ad1, b1, W2, as2, ad2, b2,
                                    w1t, prm, deg, gacc, flag, N);
    k_gemm_hist<<<1250 + histBlocks, 256, 0, stream>>>(x, w1t, prm, ei, flag, h1,
                                                       asrc1f, adst1f, deg, epos, E, Etot);
    k_scan<<<(N + 255) / 256, 256, 0, stream>>>(deg, rowptr, N);
    k_scatter<<<histBlocks, 256, 0, stream>>>(ei, rowptr, epos, csr_src, E, Etot);
    k_agg1<<<N / 4, 256, 0, stream>>>(h1, asrc1f, adst1f, rowptr, csr_src, prm,
                                      h2, asrc2f, adst2f);
    k_agg2f<<<N / 16, 256, 0, stream>>>(h2, asrc2f, adst2f, rowptr, csr_src, prm,
                                        batch, gacc, gcnt, donecnt, flag, d_out);
}